// Round 9
// baseline (536.604 us; speedup 1.0000x reference)
//
#include <hip/hip_runtime.h>

#define MAXDEG 64
#define BINSHIFT 10
#define CAP 20480        // per-bin capacity; mean 16326, +32 sigma
#define CHUNK 4096       // edges per bin_edges block

typedef __bf16 bf16x8 __attribute__((ext_vector_type(8)));
typedef float f32x4 __attribute__((ext_vector_type(4)));

__device__ inline ushort f2bf(float f) {
    unsigned u = __builtin_bit_cast(unsigned, f);
    return (ushort)((u + 0x7fffu + ((u >> 16) & 1u)) >> 16);
}
__device__ inline float bf2f(ushort h) {
    unsigned u = ((unsigned)h) << 16;
    return __builtin_bit_cast(float, u);
}

// ---------------------------------------------------------------------------
// Phase 1: block-local LDS histogram -> one range-reservation atomic per
// (block,bin) -> contiguous runs written to binbuf.
// ---------------------------------------------------------------------------
__global__ __launch_bounds__(256) void bin_edges(
    const int* __restrict__ src, const int* __restrict__ dst,
    int* __restrict__ bincnt, uint2* __restrict__ binbuf, int E)
{
    __shared__ int hist[128];
    __shared__ int base[128];
    const int t = threadIdx.x;
    if (t < 128) hist[t] = 0;
    __syncthreads();

    const int e0 = blockIdx.x * CHUNK;
    int s[16], d[16], sl[16];
    #pragma unroll
    for (int j = 0; j < 16; ++j) {
        int e = e0 + j * 256 + t;
        if (e < E) {
            s[j]  = src[e];
            d[j]  = dst[e];
            sl[j] = atomicAdd(&hist[d[j] >> BINSHIFT], 1);
        } else {
            d[j] = -1;
        }
    }
    __syncthreads();
    if (t < 128 && hist[t] > 0) base[t] = atomicAdd(&bincnt[t], hist[t]);
    __syncthreads();
    #pragma unroll
    for (int j = 0; j < 16; ++j) {
        if (d[j] >= 0) {
            int b = d[j] >> BINSHIFT;
            int pos = base[b] + sl[j];
            if (pos < CAP)
                binbuf[(size_t)b * CAP + pos] = make_uint2((unsigned)s[j], (unsigned)d[j]);
        }
    }
}

// ---------------------------------------------------------------------------
// Phase 2: one block per bin. deg counting in LDS; col writes confined to a
// 256KB single-XCD window. deg written once (no N-sized memset).
// ---------------------------------------------------------------------------
__global__ __launch_bounds__(512) void fill_buckets(
    const int* __restrict__ bincnt, const uint2* __restrict__ binbuf,
    int* __restrict__ deg, int* __restrict__ col, int N)
{
    __shared__ int ldeg[1024];
    const int b = blockIdx.x;
    const int t = threadIdx.x;
    ldeg[t] = 0;
    ldeg[t + 512] = 0;
    __syncthreads();
    int cnt = bincnt[b];
    cnt = cnt < CAP ? cnt : CAP;
    const uint2* seg = binbuf + (size_t)b * CAP;
    for (int i = t; i < cnt; i += 512) {
        uint2 e = seg[i];
        int slot = atomicAdd(&ldeg[e.y & 1023], 1);
        if (slot < MAXDEG) col[(size_t)e.y * MAXDEG + slot] = (int)e.x;
    }
    __syncthreads();
    int nb = b << BINSHIFT;
    #pragma unroll
    for (int u = 0; u < 2; ++u) {
        int i = t + u * 512;
        int node = nb + i;
        if (node < N) deg[node] = ldeg[i];
    }
}

// ---------------------------------------------------------------------------
// Elementwise f32 -> (hi,lo) bf16 split planes. i covers n/4 float4s.
// ---------------------------------------------------------------------------
__global__ __launch_bounds__(256) void xsplit(
    const float* __restrict__ X, ushort* __restrict__ Hi, ushort* __restrict__ Lo, int n4)
{
    int i = blockIdx.x * 256 + threadIdx.x;
    if (i >= n4) return;
    float4 v = *(const float4*)(X + (size_t)i * 4);
    ushort h0 = f2bf(v.x), h1 = f2bf(v.y), h2 = f2bf(v.z), h3 = f2bf(v.w);
    *(ushort4*)(Hi + (size_t)i * 4) = make_ushort4(h0, h1, h2, h3);
    *(ushort4*)(Lo + (size_t)i * 4) = make_ushort4(
        f2bf(v.x - bf2f(h0)), f2bf(v.y - bf2f(h1)),
        f2bf(v.z - bf2f(h2)), f2bf(v.w - bf2f(h3)));
}

// ---------------------------------------------------------------------------
// Weight transpose+split: T[n][k] = split(W[k][n]).
// ---------------------------------------------------------------------------
__global__ __launch_bounds__(256) void wsplit(
    const float* __restrict__ W, ushort* __restrict__ Thi, ushort* __restrict__ Tlo,
    int K, int N)
{
    int idx = blockIdx.x * 256 + threadIdx.x;
    if (idx >= K * N) return;
    int n = idx / K, k = idx % K;
    float v = W[(size_t)k * N + n];
    ushort h = f2bf(v);
    Thi[idx] = h;
    Tlo[idx] = f2bf(v - bf2f(h));
}

__global__ void make_bcat(const float* __restrict__ b2, float* __restrict__ bcat) {
    int t = threadIdx.x;
    bcat[t] = t < 128 ? 0.f : b2[t - 128];
}

__global__ __launch_bounds__(256) void init_logits(
    const float* __restrict__ bc2, float* __restrict__ out, int M)
{
    int n = blockIdx.x * 256 + threadIdx.x;
    if (n < M) *(float2*)(out + (size_t)n * 2) = make_float2(bc2[0], bc2[1]);
}

// ---------------------------------------------------------------------------
// Mean-aggregate (C=128) from a bf16 plane -> bf16 hi/lo pair out.
// One wave per node, 2 elems/lane.
// ---------------------------------------------------------------------------
__global__ __launch_bounds__(256) void agg_mean_pair(
    const ushort* __restrict__ Xb, const int* __restrict__ col,
    const int* __restrict__ deg, ushort* __restrict__ Ohi, ushort* __restrict__ Olo, int N)
{
    int gw = (blockIdx.x * 256 + threadIdx.x) >> 6;
    if (gw >= N) return;
    int lane = threadIdx.x & 63;
    int d = deg[gw];
    int dc = d < MAXDEG ? d : MAXDEG;
    const int* cl = col + (size_t)gw * MAXDEG;
    float a0 = 0.f, a1 = 0.f;
    int i = 0;
    for (; i + 4 <= dc; i += 4) {
        int4 id4 = *(const int4*)(cl + i);
        ushort2 v0 = *(const ushort2*)(Xb + (size_t)id4.x * 128 + lane * 2);
        ushort2 v1 = *(const ushort2*)(Xb + (size_t)id4.y * 128 + lane * 2);
        ushort2 v2 = *(const ushort2*)(Xb + (size_t)id4.z * 128 + lane * 2);
        ushort2 v3 = *(const ushort2*)(Xb + (size_t)id4.w * 128 + lane * 2);
        a0 += (bf2f(v0.x) + bf2f(v1.x)) + (bf2f(v2.x) + bf2f(v3.x));
        a1 += (bf2f(v0.y) + bf2f(v1.y)) + (bf2f(v2.y) + bf2f(v3.y));
    }
    for (; i < dc; ++i) {
        ushort2 v = *(const ushort2*)(Xb + (size_t)cl[i] * 128 + lane * 2);
        a0 += bf2f(v.x); a1 += bf2f(v.y);
    }
    float inv = 1.0f / (float)(d > 1 ? d : 1);
    float m0 = a0 * inv, m1 = a1 * inv;
    ushort h0 = f2bf(m0), h1 = f2bf(m1);
    *(ushort2*)(Ohi + (size_t)gw * 128 + lane * 2) = make_ushort2(h0, h1);
    *(ushort2*)(Olo + (size_t)gw * 128 + lane * 2) =
        make_ushort2(f2bf(m0 - bf2f(h0)), f2bf(m1 - bf2f(h1)));
}

// ---------------------------------------------------------------------------
// agg_finish: h2[n][c] = mean_{s} tcat[s][c] + tcat[n][128+c]
// writes f32 h2 (d_out) AND bf16 hi/lo pair (classifier A input)
// ---------------------------------------------------------------------------
__global__ __launch_bounds__(256) void agg_finish(
    const float* __restrict__ tcat, const int* __restrict__ col,
    const int* __restrict__ deg, float* __restrict__ h2,
    ushort* __restrict__ Ohi, ushort* __restrict__ Olo, int N)
{
    int gw = (blockIdx.x * 256 + threadIdx.x) >> 6;
    if (gw >= N) return;
    int lane = threadIdx.x & 63;
    int d = deg[gw];
    int dc = d < MAXDEG ? d : MAXDEG;
    const int* cl = col + (size_t)gw * MAXDEG;
    float a0 = 0.f, a1 = 0.f;
    int i = 0;
    for (; i + 4 <= dc; i += 4) {
        int4 id4 = *(const int4*)(cl + i);
        float2 v0 = *(const float2*)(tcat + (size_t)id4.x * 256 + lane * 2);
        float2 v1 = *(const float2*)(tcat + (size_t)id4.y * 256 + lane * 2);
        float2 v2 = *(const float2*)(tcat + (size_t)id4.z * 256 + lane * 2);
        float2 v3 = *(const float2*)(tcat + (size_t)id4.w * 256 + lane * 2);
        a0 += (v0.x + v1.x) + (v2.x + v3.x);
        a1 += (v0.y + v1.y) + (v2.y + v3.y);
    }
    for (; i < dc; ++i) {
        float2 v = *(const float2*)(tcat + (size_t)cl[i] * 256 + lane * 2);
        a0 += v.x; a1 += v.y;
    }
    float inv = 1.0f / (float)(d > 1 ? d : 1);
    float2 hp = *(const float2*)(tcat + (size_t)gw * 256 + 128 + lane * 2);
    float r0 = a0 * inv + hp.x, r1 = a1 * inv + hp.y;
    *(float2*)(h2 + (size_t)gw * 128 + lane * 2) = make_float2(r0, r1);
    ushort h0 = f2bf(r0), h1 = f2bf(r1);
    *(ushort2*)(Ohi + (size_t)gw * 128 + lane * 2) = make_ushort2(h0, h1);
    *(ushort2*)(Olo + (size_t)gw * 128 + lane * 2) =
        make_ushort2(f2bf(r0 - bf2f(h0)), f2bf(r1 - bf2f(h1)));
}

// ---------------------------------------------------------------------------
// LDS-staged split-bf16 MFMA GEMM, BM=256, BN=256(full), BK=32.
// A and B are PRE-SPLIT global bf16 hi/lo planes [M][K]/[256][K] -> staging
// is pure uint4 copies (no VALU split in the k0 loop).
// 512 threads = 8 waves (4M x 2N), wave tile 64x128 (4mi x 8nj of 16x16).
// Each k-tile staged ONCE, reused by 3 passes: Ahi*Bhi + Alo*Bhi + Ahi*Blo.
// LDS rows padded to 40 ushorts (80B) -> conflict-free reads/writes.
// Epilogue: f32 out and/or bf16 pair out; LOGITS=1: fused classifier
//   (relu(acc+bias) . (sw0|sw1), shfl-reduce, atomicAdd into bc2-init out).
// ---------------------------------------------------------------------------
template<int K, int NPH, int LOGITS>
__global__ __launch_bounds__(512, 1) void gemm_tile(
    const ushort* __restrict__ A1hi, const ushort* __restrict__ A1lo,
    const ushort* __restrict__ A2hi, const ushort* __restrict__ A2lo,
    const ushort* __restrict__ B1hi, const ushort* __restrict__ B1lo,
    const ushort* __restrict__ B2hi, const ushort* __restrict__ B2lo,
    const float* __restrict__ bias, const float* __restrict__ Wc2,
    float* __restrict__ outf, ushort* __restrict__ outhi, ushort* __restrict__ outlo,
    int M, int relu)
{
    __shared__ __align__(16) ushort Ah[256 * 40];
    __shared__ __align__(16) ushort Al[256 * 40];
    __shared__ __align__(16) ushort BhS[256 * 40];
    __shared__ __align__(16) ushort BlS[256 * 40];
    __shared__ float sw0[256], sw1[256];

    const int t = threadIdx.x;
    if constexpr (LOGITS) {
        if (t < 256) {
            sw0[t] = Wc2[t * 2 + 0];
            sw1[t] = Wc2[t * 2 + 1];
        }
    }

    const int m0 = blockIdx.x * 256;
    const int l  = t & 63;
    const int wv = t >> 6;
    const int wr = (wv >> 1) * 64;     // wave row base (0..192)
    const int wc = (wv & 1) * 128;     // wave col base (0 or 128)
    const int lr = l & 15;
    const int kb = l >> 4;

    const int sr = t >> 1;             // staging row 0..255
    const int sh = t & 1;              // staging k-half

    f32x4 acc[4][8] = {};

    #pragma unroll
    for (int ph = 0; ph < NPH; ++ph) {
        const ushort* Ahi_ = ph ? A2hi : A1hi;
        const ushort* Alo_ = ph ? A2lo : A1lo;
        const ushort* Bh_  = ph ? B2hi : B1hi;
        const ushort* Bl_  = ph ? B2lo : B1lo;
        for (int k0 = 0; k0 < K; k0 += 32) {
            __syncthreads();
            // stage A pair (pure copies)
            {
                int rg = m0 + sr;
                rg = rg < M ? rg : M - 1;
                size_t goff = (size_t)rg * K + k0 + sh * 16;
                int base = sr * 40 + sh * 16;
                *(uint4*)&Ah[base]     = *(const uint4*)(Ahi_ + goff);
                *(uint4*)&Ah[base + 8] = *(const uint4*)(Ahi_ + goff + 8);
                *(uint4*)&Al[base]     = *(const uint4*)(Alo_ + goff);
                *(uint4*)&Al[base + 8] = *(const uint4*)(Alo_ + goff + 8);
            }
            // stage B pair
            {
                size_t goff = (size_t)sr * K + k0 + sh * 16;
                int base = sr * 40 + sh * 16;
                *(uint4*)&BhS[base]     = *(const uint4*)(Bh_ + goff);
                *(uint4*)&BhS[base + 8] = *(const uint4*)(Bh_ + goff + 8);
                *(uint4*)&BlS[base]     = *(const uint4*)(Bl_ + goff);
                *(uint4*)&BlS[base + 8] = *(const uint4*)(Bl_ + goff + 8);
            }
            __syncthreads();
            // compute: hoist A frags, loop nj
            bf16x8 ah[4], al_[4];
            #pragma unroll
            for (int mi = 0; mi < 4; ++mi) {
                int off = (wr + mi * 16 + lr) * 40 + kb * 8;
                ah[mi]  = *(const bf16x8*)&Ah[off];
                al_[mi] = *(const bf16x8*)&Al[off];
            }
            #pragma unroll
            for (int nj = 0; nj < 8; ++nj) {
                int off = (wc + nj * 16 + lr) * 40 + kb * 8;
                bf16x8 bh = *(const bf16x8*)&BhS[off];
                bf16x8 bl = *(const bf16x8*)&BlS[off];
                #pragma unroll
                for (int mi = 0; mi < 4; ++mi) {
                    acc[mi][nj] = __builtin_amdgcn_mfma_f32_16x16x32_bf16(ah[mi],  bh, acc[mi][nj], 0, 0, 0);
                    acc[mi][nj] = __builtin_amdgcn_mfma_f32_16x16x32_bf16(al_[mi], bh, acc[mi][nj], 0, 0, 0);
                    acc[mi][nj] = __builtin_amdgcn_mfma_f32_16x16x32_bf16(ah[mi],  bl, acc[mi][nj], 0, 0, 0);
                }
            }
        }
    }

    // D map: col = l&15, row = (l>>4)*4 + reg
    if constexpr (!LOGITS) {
        #pragma unroll
        for (int nj = 0; nj < 8; ++nj) {
            int colg = wc + nj * 16 + lr;
            float bv = bias[colg];
            #pragma unroll
            for (int mi = 0; mi < 4; ++mi) {
                #pragma unroll
                for (int reg = 0; reg < 4; ++reg) {
                    int rowg = m0 + wr + mi * 16 + kb * 4 + reg;
                    if (rowg >= M) continue;
                    float v = acc[mi][nj][reg] + bv;
                    if (relu) v = fmaxf(v, 0.f);
                    if (outf) outf[(size_t)rowg * 256 + colg] = v;
                    if (outhi) {
                        ushort hv = f2bf(v);
                        outhi[(size_t)rowg * 256 + colg] = hv;
                        outlo[(size_t)rowg * 256 + colg] = f2bf(v - bf2f(hv));
                    }
                }
            }
        }
    } else {
        #pragma unroll
        for (int mi = 0; mi < 4; ++mi) {
            #pragma unroll
            for (int reg = 0; reg < 4; ++reg) {
                float s0 = 0.f, s1 = 0.f;
                #pragma unroll
                for (int nj = 0; nj < 8; ++nj) {
                    int colg = wc + nj * 16 + lr;
                    float v = fmaxf(acc[mi][nj][reg] + bias[colg], 0.f);
                    s0 += v * sw0[colg];
                    s1 += v * sw1[colg];
                }
                #pragma unroll
                for (int mk = 1; mk < 16; mk <<= 1) {
                    s0 += __shfl_xor(s0, mk);
                    s1 += __shfl_xor(s1, mk);
                }
                int rowg = m0 + wr + mi * 16 + kb * 4 + reg;
                if (lr == 0 && rowg < M) {
                    atomicAdd(&outf[(size_t)rowg * 2 + 0], s0);
                    atomicAdd(&outf[(size_t)rowg * 2 + 1], s1);
                }
            }
        }
    }
}

// ---------------------------------------------------------------------------
extern "C" void kernel_launch(void* const* d_in, const int* in_sizes, int n_in,
                              void* d_out, int out_size, void* d_ws, size_t ws_size,
                              hipStream_t stream)
{
    const float* x   = (const float*)d_in[0];
    const int*   ei  = (const int*)d_in[1];
    const float* Wl1 = (const float*)d_in[2];
    const float* Wr1 = (const float*)d_in[3];
    const float* b1  = (const float*)d_in[4];
    const float* Wl2 = (const float*)d_in[5];
    const float* Wr2 = (const float*)d_in[6];
    const float* b2  = (const float*)d_in[7];
    const float* Wc1 = (const float*)d_in[8];
    const float* bc1 = (const float*)d_in[9];
    const float* Wc2 = (const float*)d_in[10];
    const float* bc2 = (const float*)d_in[11];

    const int N = in_sizes[0] / 128;   // 100000
    const int E = in_sizes[1] / 2;     // 1600000
    const int nbins = (N + (1 << BINSHIFT) - 1) >> BINSHIFT;   // 98

    char* ws = (char*)d_ws;
    size_t off = 0;
    auto alloc = [&](size_t bytes) -> void* {
        void* p = ws + off;
        off += (bytes + 255) & ~(size_t)255;
        return p;
    };
    const size_t NE128 = (size_t)N * 128;
    const size_t NE256 = (size_t)N * 256;

    int*    bincnt = (int*)alloc((size_t)nbins * 4);
    int*    deg  = (int*)alloc((size_t)N * 4);
    int*    colb = (int*)alloc((size_t)N * MAXDEG * 4);
    float*  bufA = (float*)alloc(NE256 * 4);   // binbuf -> {x pair, a1 pair} -> tcat -> (free)
    float*  bufB = (float*)alloc(NE256 * 4);   // h1 pair -> h2 pair
    ushort* wl1h = (ushort*)alloc(256 * 128 * 2); ushort* wl1l = (ushort*)alloc(256 * 128 * 2);
    ushort* wr1h = (ushort*)alloc(256 * 128 * 2); ushort* wr1l = (ushort*)alloc(256 * 128 * 2);
    ushort* w2h  = (ushort*)alloc(256 * 256 * 2); ushort* w2l  = (ushort*)alloc(256 * 256 * 2);
    ushort* wc1h = (ushort*)alloc(256 * 128 * 2); ushort* wc1l = (ushort*)alloc(256 * 128 * 2);
    float*  bcat = (float*)alloc(256 * 4);

    uint2*  binbuf = (uint2*)bufA;                 // 16MB, dead after fill_buckets
    ushort* xs_hi  = (ushort*)bufA;                // [N][128] bf16
    ushort* xs_lo  = (ushort*)bufA + NE128;
    ushort* a1_hi  = (ushort*)bufA + 2 * NE128;
    ushort* a1_lo  = (ushort*)bufA + 3 * NE128;
    float*  tcat   = bufA;                         // [N][256] f32 (x/a1 pairs dead)
    ushort* h1_hi  = (ushort*)bufB;                // [N][256] pair
    ushort* h1_lo  = (ushort*)bufB + NE256;
    ushort* h2_hi  = (ushort*)bufB;                // [N][128] pair (h1 dead)
    ushort* h2_lo  = (ushort*)bufB + NE128;

    float* h2     = (float*)d_out;                   // [N][128]  (output 0)
    float* logits = (float*)d_out + NE128;           // [N][2]    (output 1)

    const int gm = (N + 255) / 256;                  // 391

    hipMemsetAsync(bincnt, 0, (size_t)nbins * 4, stream);

    // two-phase bucket build
    bin_edges<<<dim3((E + CHUNK - 1) / CHUNK), dim3(256), 0, stream>>>(
        ei, ei + E, bincnt, binbuf, E);
    fill_buckets<<<dim3(nbins), dim3(512), 0, stream>>>(bincnt, binbuf, deg, colb, N);

    // prep: x pair (after fill_buckets frees binbuf region) + weights
    xsplit<<<dim3((int)(NE128 / 4 + 255) / 256), dim3(256), 0, stream>>>(
        x, xs_hi, xs_lo, (int)(NE128 / 4));
    wsplit<<<dim3(128), dim3(256), 0, stream>>>(Wl1, wl1h, wl1l, 128, 256);
    wsplit<<<dim3(128), dim3(256), 0, stream>>>(Wr1, wr1h, wr1l, 128, 256);
    wsplit<<<dim3(128), dim3(256), 0, stream>>>(Wl2, w2h, w2l, 256, 128);
    wsplit<<<dim3(128), dim3(256), 0, stream>>>(Wr2, w2h + 128 * 256, w2l + 128 * 256, 256, 128);
    wsplit<<<dim3(128), dim3(256), 0, stream>>>(Wc1, wc1h, wc1l, 128, 256);
    make_bcat<<<dim3(1), dim3(256), 0, stream>>>(b2, bcat);
    init_logits<<<dim3((N + 255) / 256), dim3(256), 0, stream>>>(bc2, logits, N);

    // Layer 1: h1 = relu(mean(x)@Wl1 + x@Wr1 + b1) -> pair [N][256]
    agg_mean_pair<<<dim3((N + 3) / 4), dim3(256), 0, stream>>>(
        xs_hi, colb, deg, a1_hi, a1_lo, N);
    gemm_tile<128, 2, 0><<<dim3(gm), dim3(512), 0, stream>>>(
        a1_hi, a1_lo, xs_hi, xs_lo, wl1h, wl1l, wr1h, wr1l,
        b1, nullptr, nullptr, h1_hi, h1_lo, N, 1);

    // Layer 2 fused: tcat = [h1@Wl2 | h1@Wr2 + b2]  f32 [N][256]
    gemm_tile<256, 1, 0><<<dim3(gm), dim3(512), 0, stream>>>(
        h1_hi, h1_lo, nullptr, nullptr, w2h, w2l, nullptr, nullptr,
        bcat, nullptr, tcat, nullptr, nullptr, N, 0);

    // h2 = mean(t2) + h2p -> d_out f32 + pair (h1 slab free)
    agg_finish<<<dim3((N + 3) / 4), dim3(256), 0, stream>>>(
        tcat, colb, deg, h2, h2_hi, h2_lo, N);

    // Classifier fused: logits += relu(h2@Wc1 + bc1) @ Wc2  (bc2 pre-init)
    gemm_tile<128, 1, 1><<<dim3(gm), dim3(512), 0, stream>>>(
        h2_hi, h2_lo, nullptr, nullptr, wc1h, wc1l, nullptr, nullptr,
        bc1, Wc2, logits, nullptr, nullptr, N, 1);
}

// Round 10
// 532.743 us; speedup vs baseline: 1.0072x; 1.0072x over previous
//
#include <hip/hip_runtime.h>

#define MAXDEG 64
#define BINSHIFT 10
#define CAP 20480        // per-bin capacity; mean 16326, +32 sigma
#define CHUNK 4096       // edges per bin_edges block

typedef __bf16 bf16x8 __attribute__((ext_vector_type(8)));
typedef float f32x4 __attribute__((ext_vector_type(4)));

__device__ inline ushort f2bf(float f) {
    unsigned u = __builtin_bit_cast(unsigned, f);
    return (ushort)((u + 0x7fffu + ((u >> 16) & 1u)) >> 16);
}
__device__ inline float bf2f(ushort h) {
    unsigned u = ((unsigned)h) << 16;
    return __builtin_bit_cast(float, u);
}
__device__ inline unsigned packbf(float v) {
    ushort h = f2bf(v);
    ushort l = f2bf(v - bf2f(h));
    return (unsigned)h | ((unsigned)l << 16);
}
// assemble hi/lo ushort pairs from two packed elems (u0 = elem j, u1 = elem j+1)
__device__ inline unsigned phi(unsigned u1, unsigned u0) { return __builtin_amdgcn_perm(u1, u0, 0x05040100u); }
__device__ inline unsigned plo(unsigned u1, unsigned u0) { return __builtin_amdgcn_perm(u1, u0, 0x07060302u); }

// ---------------------------------------------------------------------------
// Phase 1: block-local LDS histogram -> one range-reservation atomic per
// (block,bin) -> contiguous runs written to binbuf.
// ---------------------------------------------------------------------------
__global__ __launch_bounds__(256) void bin_edges(
    const int* __restrict__ src, const int* __restrict__ dst,
    int* __restrict__ bincnt, uint2* __restrict__ binbuf, int E)
{
    __shared__ int hist[128];
    __shared__ int base[128];
    const int t = threadIdx.x;
    if (t < 128) hist[t] = 0;
    __syncthreads();

    const int e0 = blockIdx.x * CHUNK;
    int s[16], d[16], sl[16];
    #pragma unroll
    for (int j = 0; j < 16; ++j) {
        int e = e0 + j * 256 + t;
        if (e < E) {
            s[j]  = src[e];
            d[j]  = dst[e];
            sl[j] = atomicAdd(&hist[d[j] >> BINSHIFT], 1);
        } else {
            d[j] = -1;
        }
    }
    __syncthreads();
    if (t < 128 && hist[t] > 0) base[t] = atomicAdd(&bincnt[t], hist[t]);
    __syncthreads();
    #pragma unroll
    for (int j = 0; j < 16; ++j) {
        if (d[j] >= 0) {
            int b = d[j] >> BINSHIFT;
            int pos = base[b] + sl[j];
            if (pos < CAP)
                binbuf[(size_t)b * CAP + pos] = make_uint2((unsigned)s[j], (unsigned)d[j]);
        }
    }
}

// ---------------------------------------------------------------------------
// Phase 2: one block per bin. deg counting in LDS; col writes confined to a
// 256KB single-XCD window. deg written once (no N-sized memset).
// ---------------------------------------------------------------------------
__global__ __launch_bounds__(512) void fill_buckets(
    const int* __restrict__ bincnt, const uint2* __restrict__ binbuf,
    int* __restrict__ deg, int* __restrict__ col, int N)
{
    __shared__ int ldeg[1024];
    const int b = blockIdx.x;
    const int t = threadIdx.x;
    ldeg[t] = 0;
    ldeg[t + 512] = 0;
    __syncthreads();
    int cnt = bincnt[b];
    cnt = cnt < CAP ? cnt : CAP;
    const uint2* seg = binbuf + (size_t)b * CAP;
    for (int i = t; i < cnt; i += 512) {
        uint2 e = seg[i];
        int slot = atomicAdd(&ldeg[e.y & 1023], 1);
        if (slot < MAXDEG) col[(size_t)e.y * MAXDEG + slot] = (int)e.x;
    }
    __syncthreads();
    int nb = b << BINSHIFT;
    #pragma unroll
    for (int u = 0; u < 2; ++u) {
        int i = t + u * 512;
        int node = nb + i;
        if (node < N) deg[node] = ldeg[i];
    }
}

// ---------------------------------------------------------------------------
// x (f32) -> packed pair plane (GEMM operand) + bf16-hi plane (gather source)
// ---------------------------------------------------------------------------
__global__ __launch_bounds__(256) void xsplit(
    const float* __restrict__ X, unsigned* __restrict__ Xp,
    ushort* __restrict__ Xb, int n4)
{
    int i = blockIdx.x * 256 + threadIdx.x;
    if (i >= n4) return;
    float4 v = *(const float4*)(X + (size_t)i * 4);
    unsigned p0 = packbf(v.x), p1 = packbf(v.y), p2 = packbf(v.z), p3 = packbf(v.w);
    *(uint4*)(Xp + (size_t)i * 4) = make_uint4(p0, p1, p2, p3);
    *(ushort4*)(Xb + (size_t)i * 4) = make_ushort4(
        (ushort)p0, (ushort)p1, (ushort)p2, (ushort)p3);
}

// ---------------------------------------------------------------------------
// Weight transpose + packed split: T[n][k] = pack(W[k][n]).
// ---------------------------------------------------------------------------
__global__ __launch_bounds__(256) void wsplit(
    const float* __restrict__ W, unsigned* __restrict__ Tp, int K, int N)
{
    int idx = blockIdx.x * 256 + threadIdx.x;
    if (idx >= K * N) return;
    int n = idx / K, k = idx % K;
    Tp[idx] = packbf(W[(size_t)k * N + n]);
}

__global__ void make_bcat(const float* __restrict__ b2, float* __restrict__ bcat) {
    int t = threadIdx.x;
    bcat[t] = t < 128 ? 0.f : b2[t - 128];
}

__global__ __launch_bounds__(256) void init_logits(
    const float* __restrict__ bc2, float* __restrict__ out, int M)
{
    int n = blockIdx.x * 256 + threadIdx.x;
    if (n < M) *(float2*)(out + (size_t)n * 2) = make_float2(bc2[0], bc2[1]);
}

// ---------------------------------------------------------------------------
// Mean-aggregate (C=128) from bf16-hi plane -> packed pair out.
// One wave per node, 2 elems/lane.
// ---------------------------------------------------------------------------
__global__ __launch_bounds__(256) void agg_mean_packed(
    const ushort* __restrict__ Xb, const int* __restrict__ col,
    const int* __restrict__ deg, unsigned* __restrict__ Op, int N)
{
    int gw = (blockIdx.x * 256 + threadIdx.x) >> 6;
    if (gw >= N) return;
    int lane = threadIdx.x & 63;
    int d = deg[gw];
    int dc = d < MAXDEG ? d : MAXDEG;
    const int* cl = col + (size_t)gw * MAXDEG;
    float a0 = 0.f, a1 = 0.f;
    int i = 0;
    for (; i + 4 <= dc; i += 4) {
        int4 id4 = *(const int4*)(cl + i);
        ushort2 v0 = *(const ushort2*)(Xb + (size_t)id4.x * 128 + lane * 2);
        ushort2 v1 = *(const ushort2*)(Xb + (size_t)id4.y * 128 + lane * 2);
        ushort2 v2 = *(const ushort2*)(Xb + (size_t)id4.z * 128 + lane * 2);
        ushort2 v3 = *(const ushort2*)(Xb + (size_t)id4.w * 128 + lane * 2);
        a0 += (bf2f(v0.x) + bf2f(v1.x)) + (bf2f(v2.x) + bf2f(v3.x));
        a1 += (bf2f(v0.y) + bf2f(v1.y)) + (bf2f(v2.y) + bf2f(v3.y));
    }
    for (; i < dc; ++i) {
        ushort2 v = *(const ushort2*)(Xb + (size_t)cl[i] * 128 + lane * 2);
        a0 += bf2f(v.x); a1 += bf2f(v.y);
    }
    float inv = 1.0f / (float)(d > 1 ? d : 1);
    *(uint2*)(Op + (size_t)gw * 128 + lane * 2) =
        make_uint2(packbf(a0 * inv), packbf(a1 * inv));
}

// ---------------------------------------------------------------------------
// agg_finish: h2[n][c] = mean_{s} tcat[s][c] + tcat[n][128+c]
// writes f32 h2 (d_out) AND packed pair (classifier A input)
// ---------------------------------------------------------------------------
__global__ __launch_bounds__(256) void agg_finish(
    const float* __restrict__ tcat, const int* __restrict__ col,
    const int* __restrict__ deg, float* __restrict__ h2,
    unsigned* __restrict__ Op, int N)
{
    int gw = (blockIdx.x * 256 + threadIdx.x) >> 6;
    if (gw >= N) return;
    int lane = threadIdx.x & 63;
    int d = deg[gw];
    int dc = d < MAXDEG ? d : MAXDEG;
    const int* cl = col + (size_t)gw * MAXDEG;
    float a0 = 0.f, a1 = 0.f;
    int i = 0;
    for (; i + 4 <= dc; i += 4) {
        int4 id4 = *(const int4*)(cl + i);
        float2 v0 = *(const float2*)(tcat + (size_t)id4.x * 256 + lane * 2);
        float2 v1 = *(const float2*)(tcat + (size_t)id4.y * 256 + lane * 2);
        float2 v2 = *(const float2*)(tcat + (size_t)id4.z * 256 + lane * 2);
        float2 v3 = *(const float2*)(tcat + (size_t)id4.w * 256 + lane * 2);
        a0 += (v0.x + v1.x) + (v2.x + v3.x);
        a1 += (v0.y + v1.y) + (v2.y + v3.y);
    }
    for (; i < dc; ++i) {
        float2 v = *(const float2*)(tcat + (size_t)cl[i] * 256 + lane * 2);
        a0 += v.x; a1 += v.y;
    }
    float inv = 1.0f / (float)(d > 1 ? d : 1);
    float2 hp = *(const float2*)(tcat + (size_t)gw * 256 + 128 + lane * 2);
    float r0 = a0 * inv + hp.x, r1 = a1 * inv + hp.y;
    *(float2*)(h2 + (size_t)gw * 128 + lane * 2) = make_float2(r0, r1);
    *(uint2*)(Op + (size_t)gw * 128 + lane * 2) = make_uint2(packbf(r0), packbf(r1));
}

// ---------------------------------------------------------------------------
// LDS-staged split-bf16 MFMA GEMM, BM=256, BN=256(full), BK=32.
// A/B operands are PACKED pair planes [rows][K] u32 (hi | lo<<16): staging
// loads uint4 and v_perm-unpacks into hi/lo LDS tiles (1 op / 2 elems).
// 512 threads = 8 waves (4M x 2N), wave tile 64x128 (4mi x 8nj of 16x16).
// Each k-tile staged ONCE, reused by 3 passes: Ahi*Bhi + Alo*Bhi + Ahi*Blo.
// LDS rows padded to 40 ushorts (80B) -> <=2-way (free) reads/writes.
// MODE 0: outf[M][256] f32.  MODE 2: outp packed pair (full-line u32 stores).
// MODE 1: fused classifier (relu(acc+bias).(sw0|sw1), shfl-reduce, atomicAdd).
// ---------------------------------------------------------------------------
template<int K, int NPH, int MODE>
__global__ __launch_bounds__(512, 1) void gemm_tile(
    const unsigned* __restrict__ A1, const unsigned* __restrict__ A2,
    const unsigned* __restrict__ B1, const unsigned* __restrict__ B2,
    const float* __restrict__ bias, const float* __restrict__ Wc2,
    float* __restrict__ outf, unsigned* __restrict__ outp, int M, int relu)
{
    __shared__ __align__(16) ushort Ah[256 * 40];
    __shared__ __align__(16) ushort Al[256 * 40];
    __shared__ __align__(16) ushort BhS[256 * 40];
    __shared__ __align__(16) ushort BlS[256 * 40];
    __shared__ float sw0[256], sw1[256];

    const int t = threadIdx.x;
    if constexpr (MODE == 1) {
        if (t < 256) {
            sw0[t] = Wc2[t * 2 + 0];
            sw1[t] = Wc2[t * 2 + 1];
        }
    }

    const int m0 = blockIdx.x * 256;
    const int l  = t & 63;
    const int wv = t >> 6;
    const int wr = (wv >> 1) * 64;     // wave row base (0..192)
    const int wc = (wv & 1) * 128;     // wave col base (0 or 128)
    const int lr = l & 15;
    const int kb = l >> 4;

    const int sr = t >> 1;             // staging row 0..255
    const int sh = t & 1;              // staging k-half

    f32x4 acc[4][8] = {};

    #pragma unroll
    for (int ph = 0; ph < NPH; ++ph) {
        const unsigned* Ap = ph ? A2 : A1;
        const unsigned* Bp = ph ? B2 : B1;
        for (int k0 = 0; k0 < K; k0 += 32) {
            __syncthreads();
            // stage A: uint4 loads + perm unpack -> Ah/Al
            {
                int rg = m0 + sr;
                rg = rg < M ? rg : M - 1;
                const unsigned* p = Ap + (size_t)rg * K + k0 + sh * 16;
                uint4 q0 = *(const uint4*)p;
                uint4 q1 = *(const uint4*)(p + 4);
                uint4 q2 = *(const uint4*)(p + 8);
                uint4 q3 = *(const uint4*)(p + 12);
                int base = sr * 40 + sh * 16;
                *(uint4*)&Ah[base]     = make_uint4(phi(q0.y,q0.x), phi(q0.w,q0.z), phi(q1.y,q1.x), phi(q1.w,q1.z));
                *(uint4*)&Ah[base + 8] = make_uint4(phi(q2.y,q2.x), phi(q2.w,q2.z), phi(q3.y,q3.x), phi(q3.w,q3.z));
                *(uint4*)&Al[base]     = make_uint4(plo(q0.y,q0.x), plo(q0.w,q0.z), plo(q1.y,q1.x), plo(q1.w,q1.z));
                *(uint4*)&Al[base + 8] = make_uint4(plo(q2.y,q2.x), plo(q2.w,q2.z), plo(q3.y,q3.x), plo(q3.w,q3.z));
            }
            // stage B
            {
                const unsigned* p = Bp + (size_t)sr * K + k0 + sh * 16;
                uint4 q0 = *(const uint4*)p;
                uint4 q1 = *(const uint4*)(p + 4);
                uint4 q2 = *(const uint4*)(p + 8);
                uint4 q3 = *(const uint4*)(p + 12);
                int base = sr * 40 + sh * 16;
                *(uint4*)&BhS[base]     = make_uint4(phi(q0.y,q0.x), phi(q0.w,q0.z), phi(q1.y,q1.x), phi(q1.w,q1.z));
                *(uint4*)&BhS[base + 8] = make_uint4(phi(q2.y,q2.x), phi(q2.w,q2.z), phi(q3.y,q3.x), phi(q3.w,q3.z));
                *(uint4*)&BlS[base]     = make_uint4(plo(q0.y,q0.x), plo(q0.w,q0.z), plo(q1.y,q1.x), plo(q1.w,q1.z));
                *(uint4*)&BlS[base + 8] = make_uint4(plo(q2.y,q2.x), plo(q2.w,q2.z), plo(q3.y,q3.x), plo(q3.w,q3.z));
            }
            __syncthreads();
            // compute: hoist A frags, loop nj
            bf16x8 ah[4], al_[4];
            #pragma unroll
            for (int mi = 0; mi < 4; ++mi) {
                int off = (wr + mi * 16 + lr) * 40 + kb * 8;
                ah[mi]  = *(const bf16x8*)&Ah[off];
                al_[mi] = *(const bf16x8*)&Al[off];
            }
            #pragma unroll
            for (int nj = 0; nj < 8; ++nj) {
                int off = (wc + nj * 16 + lr) * 40 + kb * 8;
                bf16x8 bh = *(const bf16x8*)&BhS[off];
                bf16x8 bl = *(const bf16x8*)&BlS[off];
                #pragma unroll
                for (int mi = 0; mi < 4; ++mi) {
                    acc[mi][nj] = __builtin_amdgcn_mfma_f32_16x16x32_bf16(ah[mi],  bh, acc[mi][nj], 0, 0, 0);
                    acc[mi][nj] = __builtin_amdgcn_mfma_f32_16x16x32_bf16(al_[mi], bh, acc[mi][nj], 0, 0, 0);
                    acc[mi][nj] = __builtin_amdgcn_mfma_f32_16x16x32_bf16(ah[mi],  bl, acc[mi][nj], 0, 0, 0);
                }
            }
        }
    }

    // D map: col = l&15, row = (l>>4)*4 + reg
    if constexpr (MODE != 1) {
        #pragma unroll
        for (int nj = 0; nj < 8; ++nj) {
            int colg = wc + nj * 16 + lr;
            float bv = bias[colg];
            #pragma unroll
            for (int mi = 0; mi < 4; ++mi) {
                #pragma unroll
                for (int reg = 0; reg < 4; ++reg) {
                    int rowg = m0 + wr + mi * 16 + kb * 4 + reg;
                    if (rowg >= M) continue;
                    float v = acc[mi][nj][reg] + bv;
                    if (relu) v = fmaxf(v, 0.f);
                    if constexpr (MODE == 0) {
                        outf[(size_t)rowg * 256 + colg] = v;
                    } else {
                        outp[(size_t)rowg * 256 + colg] = packbf(v);
                    }
                }
            }
        }
    } else {
        #pragma unroll
        for (int mi = 0; mi < 4; ++mi) {
            #pragma unroll
            for (int reg = 0; reg < 4; ++reg) {
                float s0 = 0.f, s1 = 0.f;
                #pragma unroll
                for (int nj = 0; nj < 8; ++nj) {
                    int colg = wc + nj * 16 + lr;
                    float v = fmaxf(acc[mi][nj][reg] + bias[colg], 0.f);
                    s0 += v * sw0[colg];
                    s1 += v * sw1[colg];
                }
                #pragma unroll
                for (int mk = 1; mk < 16; mk <<= 1) {
                    s0 += __shfl_xor(s0, mk);
                    s1 += __shfl_xor(s1, mk);
                }
                int rowg = m0 + wr + mi * 16 + kb * 4 + reg;
                if (lr == 0 && rowg < M) {
                    atomicAdd(&outf[(size_t)rowg * 2 + 0], s0);
                    atomicAdd(&outf[(size_t)rowg * 2 + 1], s1);
                }
            }
        }
    }
}

// ---------------------------------------------------------------------------
extern "C" void kernel_launch(void* const* d_in, const int* in_sizes, int n_in,
                              void* d_out, int out_size, void* d_ws, size_t ws_size,
                              hipStream_t stream)
{
    const float* x   = (const float*)d_in[0];
    const int*   ei  = (const int*)d_in[1];
    const float* Wl1 = (const float*)d_in[2];
    const float* Wr1 = (const float*)d_in[3];
    const float* b1  = (const float*)d_in[4];
    const float* Wl2 = (const float*)d_in[5];
    const float* Wr2 = (const float*)d_in[6];
    const float* b2  = (const float*)d_in[7];
    const float* Wc1 = (const float*)d_in[8];
    const float* bc1 = (const float*)d_in[9];
    const float* Wc2 = (const float*)d_in[10];
    const float* bc2 = (const float*)d_in[11];

    const int N = in_sizes[0] / 128;   // 100000
    const int E = in_sizes[1] / 2;     // 1600000
    const int nbins = (N + (1 << BINSHIFT) - 1) >> BINSHIFT;   // 98

    char* ws = (char*)d_ws;
    size_t off = 0;
    auto alloc = [&](size_t bytes) -> void* {
        void* p = ws + off;
        off += (bytes + 255) & ~(size_t)255;
        return p;
    };
    const size_t NE128 = (size_t)N * 128;
    const size_t NE256 = (size_t)N * 256;

    int*      bincnt = (int*)alloc((size_t)nbins * 4);
    int*      deg  = (int*)alloc((size_t)N * 4);
    int*      colb = (int*)alloc((size_t)N * MAXDEG * 4);
    float*    bufA = (float*)alloc(NE256 * 4);   // binbuf -> {xp, a1p} -> tcat
    float*    bufB = (float*)alloc(NE256 * 4);   // xb -> h1p -> h2p
    unsigned* wl1p = (unsigned*)alloc(256 * 128 * 4);
    unsigned* wr1p = (unsigned*)alloc(256 * 128 * 4);
    unsigned* w2p  = (unsigned*)alloc(256 * 256 * 4);
    unsigned* wc1p = (unsigned*)alloc(256 * 128 * 4);
    float*    bcat = (float*)alloc(256 * 4);

    uint2*    binbuf = (uint2*)bufA;               // 16MB, dead after fill_buckets
    unsigned* xp   = (unsigned*)bufA;              // [N][128] packed
    unsigned* a1p  = (unsigned*)bufA + NE128;      // [N][128] packed
    float*    tcat = bufA;                         // [N][256] f32 (xp/a1p dead)
    ushort*   xb   = (ushort*)bufB;                // [N][128] bf16-hi (gather src)
    unsigned* h1p  = (unsigned*)bufB;              // [N][256] packed (xb dead)
    unsigned* h2p  = (unsigned*)bufB;              // [N][128] packed (h1p dead)

    float* h2     = (float*)d_out;                 // [N][128]  (output 0)
    float* logits = (float*)d_out + NE128;         // [N][2]    (output 1)

    const int gm = (N + 255) / 256;                // 391

    hipMemsetAsync(bincnt, 0, (size_t)nbins * 4, stream);

    // two-phase bucket build
    bin_edges<<<dim3((E + CHUNK - 1) / CHUNK), dim3(256), 0, stream>>>(
        ei, ei + E, bincnt, binbuf, E);
    fill_buckets<<<dim3(nbins), dim3(512), 0, stream>>>(bincnt, binbuf, deg, colb, N);

    // prep: x packed + hi plane (binbuf dead), weights packed
    xsplit<<<dim3((int)(NE128 / 4 + 255) / 256), dim3(256), 0, stream>>>(
        x, xp, xb, (int)(NE128 / 4));
    wsplit<<<dim3(128), dim3(256), 0, stream>>>(Wl1, wl1p, 128, 256);
    wsplit<<<dim3(128), dim3(256), 0, stream>>>(Wr1, wr1p, 128, 256);
    wsplit<<<dim3(128), dim3(256), 0, stream>>>(Wl2, w2p, 256, 128);
    wsplit<<<dim3(128), dim3(256), 0, stream>>>(Wr2, w2p + 128 * 256, 256, 128);
    wsplit<<<dim3(128), dim3(256), 0, stream>>>(Wc1, wc1p, 128, 256);
    make_bcat<<<dim3(1), dim3(256), 0, stream>>>(b2, bcat);
    init_logits<<<dim3((N + 255) / 256), dim3(256), 0, stream>>>(bc2, logits, N);

    // Layer 1: h1 = relu(mean(x)@Wl1 + x@Wr1 + b1) -> packed [N][256]
    agg_mean_packed<<<dim3((N + 3) / 4), dim3(256), 0, stream>>>(
        xb, colb, deg, a1p, N);
    gemm_tile<128, 2, 2><<<dim3(gm), dim3(512), 0, stream>>>(
        a1p, xp, wl1p, wr1p, b1, nullptr, nullptr, h1p, N, 1);

    // Layer 2 fused: tcat = [h1@Wl2 | h1@Wr2 + b2]  f32 [N][256]
    gemm_tile<256, 1, 0><<<dim3(gm), dim3(512), 0, stream>>>(
        h1p, nullptr, w2p, nullptr, bcat, nullptr, tcat, nullptr, N, 0);

    // h2 = mean(t2) + h2p -> d_out f32 + packed (h1p slab free)
    agg_finish<<<dim3((N + 3) / 4), dim3(256), 0, stream>>>(
        tcat, colb, deg, h2, h2p, N);

    // Classifier fused: logits += relu(h2@Wc1 + bc1) @ Wc2  (bc2 pre-init)
    gemm_tile<128, 1, 1><<<dim3(gm), dim3(512), 0, stream>>>(
        h2p, nullptr, wc1p, nullptr, bc1, Wc2, logits, nullptr, N, 1);
}